// Round 10
// baseline (564.481 us; speedup 1.0000x reference)
//
#include <hip/hip_runtime.h>
#include <math.h>

// Problem constants
#define BATCH   8
#define QLEN    256
#define KLEN    2048
#define KDIM    512
#define ADIMC   512
#define NHEADS  4
#define DKH     128
#define CHUNKW  4

static constexpr float INV_SCALE = 0.04419417382415922f; // 1/sqrt(512)
static constexpr float EPSV = 1e-6f;

typedef __attribute__((ext_vector_type(8))) short bf16x8;
typedef __attribute__((ext_vector_type(4))) float f32x4;

__device__ __forceinline__ unsigned short f2bf(float f) {
    unsigned u = __builtin_bit_cast(unsigned, f);
    u += 0x7fffu + ((u >> 16) & 1u);   // round-to-nearest-even
    return (unsigned short)(u >> 16);
}

// Async global->LDS, 16 B per lane. HW rule: data lands at wave-uniform
// lds base + lane*16 (no per-lane scatter) — LDS layout below is built for it.
__device__ __forceinline__ void gload_lds16(const void* g, void* l) {
    __builtin_amdgcn_global_load_lds(
        (const __attribute__((address_space(1))) void*)g,
        (__attribute__((address_space(3))) void*)l, 16, 0, 0);
}

// ---------------------------------------------------------------------------
// Elementwise f32 -> bf16 cast (4 elems/thread)
// ---------------------------------------------------------------------------
__global__ __launch_bounds__(256) void cast_bf16(
    const float* __restrict__ x, unsigned short* __restrict__ y, int n4)
{
    int i = blockIdx.x * 256 + threadIdx.x;
    if (i < n4) {
        float4 v = ((const float4*)x)[i];
        ushort4 o;
        o.x = f2bf(v.x); o.y = f2bf(v.y); o.z = f2bf(v.z); o.w = f2bf(v.w);
        ((ushort4*)y)[i] = o;
    }
}

// ---------------------------------------------------------------------------
// Transpose-cast: W [512 x 512] (k-major rows) -> WT [512 x 512] bf16, WT[n][k]
// ---------------------------------------------------------------------------
__global__ __launch_bounds__(256) void transpose_cast(
    const float* __restrict__ W, unsigned short* __restrict__ WT)
{
    __shared__ float tile[32][33];
    const int tx = threadIdx.x;          // 0..31
    const int ty = threadIdx.y;          // 0..7
    const int k0 = blockIdx.y * 32, n0 = blockIdx.x * 32;
    #pragma unroll
    for (int i = 0; i < 32; i += 8)
        tile[ty + i][tx] = W[(size_t)(k0 + ty + i) * KDIM + n0 + tx];
    __syncthreads();
    #pragma unroll
    for (int i = 0; i < 32; i += 8)
        WT[(size_t)(n0 + ty + i) * KDIM + k0 + tx] = f2bf(tile[tx][ty + i]);
}

// ---------------------------------------------------------------------------
// Staged NT MFMA core (m97-ladder structure): block computes 128x128 f32 tile
// of A[M,K] @ B[N,K]^T. 256 threads / 4 waves, each wave a 64x64 subtile.
// ---------------------------------------------------------------------------
template<int KSTEPS>
__device__ __forceinline__ void mfma_nt_staged(
    const unsigned short* __restrict__ A, const unsigned short* __restrict__ B,
    int lda, int ldb, int bm, int bn,
    unsigned short* AsLDS, unsigned short* BsLDS, f32x4 acc[4][4])
{
    const int t = threadIdx.x;
    const int wv = t >> 6, ln = t & 63;
    const int r = ln & 15, quad = ln >> 4;
    const int wm = (wv >> 1) * 64, wn = (wv & 1) * 64;
    const int srow = wv * 16 + (ln >> 2);     // staging row (+ j*64)
    const int scol = (ln & 3) * 8;            // staging col in bf16 elems (16 B)

    for (int ks = 0; ks < KSTEPS; ++ks) {
        const int k0 = ks * 32;
        #pragma unroll
        for (int j = 0; j < 2; ++j) {
            gload_lds16(A + (size_t)(bm + j * 64 + srow) * lda + k0 + scol,
                        AsLDS + (size_t)(j * 64 + wv * 16) * 32);
            gload_lds16(B + (size_t)(bn + j * 64 + srow) * ldb + k0 + scol,
                        BsLDS + (size_t)(j * 64 + wv * 16) * 32);
        }
        __syncthreads();   // drains vmcnt (DMA) + lgkm, then barrier
        bf16x8 af[4], bg[4];
        #pragma unroll
        for (int f = 0; f < 4; ++f)
            af[f] = *(const bf16x8*)(AsLDS + (size_t)(wm + f * 16 + r) * 32 + quad * 8);
        #pragma unroll
        for (int f = 0; f < 4; ++f)
            bg[f] = *(const bf16x8*)(BsLDS + (size_t)(wn + f * 16 + r) * 32 + quad * 8);
        #pragma unroll
        for (int i = 0; i < 4; ++i)
            #pragma unroll
            for (int j2 = 0; j2 < 4; ++j2)
                acc[i][j2] = __builtin_amdgcn_mfma_f32_16x16x32_bf16(
                    af[i], bg[j2], acc[i][j2], 0, 0, 0);
        __syncthreads();   // protect LDS before next-stage overwrite
    }
}

__device__ __forceinline__ void zero_acc(f32x4 acc[4][4]) {
    #pragma unroll
    for (int i = 0; i < 4; ++i)
        #pragma unroll
        for (int j = 0; j < 4; ++j)
            acc[i][j] = f32x4{0.f, 0.f, 0.f, 0.f};
}

// ---------------------------------------------------------------------------
// Projection: C[M x 1024] bf16 = A[M x 512] @ WT[1024 x 512]^T + bias
// ---------------------------------------------------------------------------
__global__ __launch_bounds__(256) void proj_mfma(
    const unsigned short* __restrict__ A, const unsigned short* __restrict__ WT,
    const float* __restrict__ bias_m, const float* __restrict__ bias_c,
    unsigned short* __restrict__ C)
{
    __shared__ unsigned short As[128 * 32];
    __shared__ unsigned short Bs[128 * 32];
    const int bm = blockIdx.y * 128, bn = blockIdx.x * 128;
    f32x4 acc[4][4]; zero_acc(acc);
    mfma_nt_staged<16>(A, WT, KDIM, KDIM, bm, bn, As, Bs, acc);
    const int wv = threadIdx.x >> 6, ln = threadIdx.x & 63;
    const int r = ln & 15, quad = ln >> 4;
    const int m0 = bm + (wv >> 1) * 64, n0 = bn + (wv & 1) * 64;
    #pragma unroll
    for (int j = 0; j < 4; ++j) {
        const int n = n0 + j * 16 + r;
        const float bv = (n < 512) ? bias_m[n] : bias_c[n - 512];
        #pragma unroll
        for (int i = 0; i < 4; ++i) {
            #pragma unroll
            for (int reg = 0; reg < 4; ++reg) {
                const int m = m0 + i * 16 + quad * 4 + reg;
                C[(size_t)m * 1024 + n] = f2bf(acc[i][j][reg] + bv);
            }
        }
    }
}

// ---------------------------------------------------------------------------
// p_choose: per batch b, p = sigmoid(qm[b] @ km[b]^T / sqrt(512) + r + noise)
// ---------------------------------------------------------------------------
__global__ __launch_bounds__(256) void pchoose_mfma(
    const unsigned short* __restrict__ qp, const unsigned short* __restrict__ kp,
    const float* __restrict__ noise, const float* __restrict__ rp,
    float* __restrict__ p)
{
    __shared__ unsigned short As[128 * 32];
    __shared__ unsigned short Bs[128 * 32];
    const int b = blockIdx.z;
    const unsigned short* A = qp + (size_t)b * QLEN * 1024;
    const unsigned short* B = kp + (size_t)b * KLEN * 1024;
    const int bm = blockIdx.y * 128, bn = blockIdx.x * 128;
    f32x4 acc[4][4]; zero_acc(acc);
    mfma_nt_staged<16>(A, B, 1024, 1024, bm, bn, As, Bs, acc);
    const int wv = threadIdx.x >> 6, ln = threadIdx.x & 63;
    const int r = ln & 15, quad = ln >> 4;
    const int m0 = bm + (wv >> 1) * 64, n0 = bn + (wv & 1) * 64;
    const float rv = rp[0];
    #pragma unroll
    for (int i = 0; i < 4; ++i) {
        #pragma unroll
        for (int reg = 0; reg < 4; ++reg) {
            const int q = m0 + i * 16 + quad * 4 + reg;
            const size_t rowoff = ((size_t)b * QLEN + q) * KLEN;
            #pragma unroll
            for (int j = 0; j < 4; ++j) {
                const int k = n0 + j * 16 + r;
                const float e = acc[i][j][reg] * INV_SCALE + rv + noise[rowoff + k];
                p[rowoff + k] = __builtin_amdgcn_rcpf(1.0f + __expf(-e));
            }
        }
    }
}

// ---------------------------------------------------------------------------
// e_chunk: per (b,h), out[b,h,q,k] = qc_h[b] @ kc_h[b]^T / sqrt(512)
// ---------------------------------------------------------------------------
__global__ __launch_bounds__(256) void echunk_mfma(
    const unsigned short* __restrict__ qp, const unsigned short* __restrict__ kp,
    float* __restrict__ out)
{
    __shared__ unsigned short As[128 * 32];
    __shared__ unsigned short Bs[128 * 32];
    const int z = blockIdx.z, b = z >> 2, h = z & 3;
    const unsigned short* A = qp + (size_t)b * QLEN * 1024 + 512 + h * DKH;
    const unsigned short* B = kp + (size_t)b * KLEN * 1024 + 512 + h * DKH;
    const int bm = blockIdx.y * 128, bn = blockIdx.x * 128;
    f32x4 acc[4][4]; zero_acc(acc);
    mfma_nt_staged<4>(A, B, 1024, 1024, bm, bn, As, Bs, acc);
    const int wv = threadIdx.x >> 6, ln = threadIdx.x & 63;
    const int r = ln & 15, quad = ln >> 4;
    const int m0 = bm + (wv >> 1) * 64, n0 = bn + (wv & 1) * 64;
    #pragma unroll
    for (int i = 0; i < 4; ++i) {
        #pragma unroll
        for (int reg = 0; reg < 4; ++reg) {
            const int q = m0 + i * 16 + quad * 4 + reg;
            const size_t rowoff = (((size_t)z) * QLEN + q) * KLEN;
            #pragma unroll
            for (int j = 0; j < 4; ++j) {
                const int k = n0 + j * 16 + r;
                out[rowoff + k] = acc[i][j][reg] * INV_SCALE;
            }
        }
    }
}

// ---------------------------------------------------------------------------
// 64-lane inclusive prefix sum via DPP (≈6 VALU ops, no LDS round-trips)
// ---------------------------------------------------------------------------
__device__ __forceinline__ float wave_incl_scan(float x)
{
#define DPP_ADD(ctrl, rmask, bctrl)                                            \
    { int _t = __builtin_amdgcn_update_dpp(0, __builtin_bit_cast(int, x),      \
                                           ctrl, rmask, 0xf, bctrl);           \
      x += __builtin_bit_cast(float, _t); }
    DPP_ADD(0x111, 0xf, true)   // row_shr:1
    DPP_ADD(0x112, 0xf, true)   // row_shr:2
    DPP_ADD(0x114, 0xf, true)   // row_shr:4
    DPP_ADD(0x118, 0xf, true)   // row_shr:8
    DPP_ADD(0x142, 0xa, false)  // row_bcast:15 -> rows 1,3
    DPP_ADD(0x143, 0xc, false)  // row_bcast:31 -> rows 2,3
#undef DPP_ADD
    return x;
}

// ---------------------------------------------------------------------------
// cumprod_mr: per (b,q) row (2048 independent blocks, fully parallel):
//   cp = exp(exclusive_cumsum(log(clip(1-p,1e-6,1))))
//   m  = p * cp ;  r = 1/clip(cp,1e-6,1)
// Fast intrinsics; absorbs ALL transcendental work off the serial scan.
// ---------------------------------------------------------------------------
__global__ __launch_bounds__(256) void cumprod_mr(
    const float* __restrict__ p, float* __restrict__ mArr, float* __restrict__ rArr)
{
    const size_t row = blockIdx.x;
    const float* pr = p + row * KLEN;
    float* mr = mArr + row * KLEN;
    float* rr = rArr + row * KLEN;
    const int tid = threadIdx.x;
    const int lane = tid & 63, wid = tid >> 6;
    __shared__ float waveTot[4];

    float4 v0 = *(const float4*)(pr + tid * 8);
    float4 v1 = *(const float4*)(pr + tid * 8 + 4);
    float pv[8] = {v0.x, v0.y, v0.z, v0.w, v1.x, v1.y, v1.z, v1.w};
    float excl[8];
    float run = 0.0f;
    #pragma unroll
    for (int j = 0; j < 8; ++j) {
        float l = __logf(fminf(fmaxf(1.0f - pv[j], EPSV), 1.0f));
        excl[j] = run;
        run += l;
    }
    float s = wave_incl_scan(run);
    if (lane == 63) waveTot[wid] = s;
    __syncthreads();
    float wex = 0.0f;
    for (int w = 0; w < wid; ++w) wex += waveTot[w];
    const float texcl = wex + s - run;

    float mv[8], rv[8];
    #pragma unroll
    for (int j = 0; j < 8; ++j) {
        const float cpv = __expf(texcl + excl[j]);
        mv[j] = pv[j] * cpv;
        rv[j] = __builtin_amdgcn_rcpf(fminf(fmaxf(cpv, EPSV), 1.0f));
    }
    *(float4*)(mr + tid * 8)     = *(float4*)&mv[0];
    *(float4*)(mr + tid * 8 + 4) = *(float4*)&mv[4];
    *(float4*)(rr + tid * 8)     = *(float4*)&rv[0];
    *(float4*)(rr + tid * 8 + 4) = *(float4*)&rv[4];
}

// ---------------------------------------------------------------------------
// alpha_scan v2: SINGLE WAVE per batch, 32 contiguous elems/lane.
// R9 post-mortem: the 8-wave version spent ~737 cyc/step, dominated by the
// cross-wave LDS exchange + 8-wave barrier (structural). Single wave deletes
// the exchange entirely: per step = two 16-deep fmaf sub-chains + one DPP
// wave scan + 32 muls + stores. Depth-3 NAMED register ring (48 float4, the
// R6 promotion pattern: named SSA + unconditional clamped refill) issues
// m/r row loads 3 steps (~1000+ cyc) ahead of use. No LDS, no barriers.
// ---------------------------------------------------------------------------
__global__ __launch_bounds__(64) void alpha_scan(
    const float* __restrict__ mArr, const float* __restrict__ rArr,
    float* __restrict__ alpha)
{
    const int b = blockIdx.x;
    const int t = threadIdx.x;   // 0..63
    const float* mrow = mArr + (size_t)b * QLEN * KLEN + t * 32;
    const float* rrow = rArr + (size_t)b * QLEN * KLEN + t * 32;
    float* arow = alpha + (size_t)b * QLEN * KLEN + t * 32;

    const float4 z4 = {0.f, 0.f, 0.f, 0.f};
    float4 a0 = z4, a1 = z4, a2 = z4, a3 = z4, a4 = z4, a5 = z4, a6 = z4, a7 = z4;
    if (t == 0) a0.x = 1.0f;   // aw_prev one-hot at k=0

#define LOADROW8(M0,M1,M2,M3,M4,M5,M6,M7, src)                                 \
    M0 = *(const float4*)((src) + 0);  M1 = *(const float4*)((src) + 4);       \
    M2 = *(const float4*)((src) + 8);  M3 = *(const float4*)((src) + 12);      \
    M4 = *(const float4*)((src) + 16); M5 = *(const float4*)((src) + 20);      \
    M6 = *(const float4*)((src) + 24); M7 = *(const float4*)((src) + 28);

    // depth-3 ring: A=row i, B=row i+1, C=row i+2 at top of step i
    float4 mA0,mA1,mA2,mA3,mA4,mA5,mA6,mA7, rA0,rA1,rA2,rA3,rA4,rA5,rA6,rA7;
    float4 mB0,mB1,mB2,mB3,mB4,mB5,mB6,mB7, rB0,rB1,rB2,rB3,rB4,rB5,rB6,rB7;
    float4 mC0,mC1,mC2,mC3,mC4,mC5,mC6,mC7, rC0,rC1,rC2,rC3,rC4,rC5,rC6,rC7;
    LOADROW8(mA0,mA1,mA2,mA3,mA4,mA5,mA6,mA7, mrow)
    LOADROW8(rA0,rA1,rA2,rA3,rA4,rA5,rA6,rA7, rrow)
    LOADROW8(mB0,mB1,mB2,mB3,mB4,mB5,mB6,mB7, mrow + KLEN)
    LOADROW8(rB0,rB1,rB2,rB3,rB4,rB5,rB6,rB7, rrow + KLEN)
    LOADROW8(mC0,mC1,mC2,mC3,mC4,mC5,mC6,mC7, mrow + 2 * KLEN)
    LOADROW8(rC0,rC1,rC2,rC3,rC4,rC5,rC6,rC7, rrow + 2 * KLEN)

#define ASTEP(I, M0,M1,M2,M3,M4,M5,M6,M7, R0,R1,R2,R3,R4,R5,R6,R7)             \
    {                                                                          \
        const int i_ = (I);                                                    \
        /* two independent 16-deep fmaf sub-chains */                          \
        float run0 = 0.0f;                                                     \
        run0 = fmaf(a0.x, R0.x, run0); const float i00 = run0;                 \
        run0 = fmaf(a0.y, R0.y, run0); const float i01 = run0;                 \
        run0 = fmaf(a0.z, R0.z, run0); const float i02 = run0;                 \
        run0 = fmaf(a0.w, R0.w, run0); const float i03 = run0;                 \
        run0 = fmaf(a1.x, R1.x, run0); const float i10 = run0;                 \
        run0 = fmaf(a1.y, R1.y, run0); const float i11 = run0;                 \
        run0 = fmaf(a1.z, R1.z, run0); const float i12 = run0;                 \
        run0 = fmaf(a1.w, R1.w, run0); const float i13 = run0;                 \
        run0 = fmaf(a2.x, R2.x, run0); const float i20 = run0;                 \
        run0 = fmaf(a2.y, R2.y, run0); const float i21 = run0;                 \
        run0 = fmaf(a2.z, R2.z, run0); const float i22 = run0;                 \
        run0 = fmaf(a2.w, R2.w, run0); const float i23 = run0;                 \
        run0 = fmaf(a3.x, R3.x, run0); const float i30 = run0;                 \
        run0 = fmaf(a3.y, R3.y, run0); const float i31 = run0;                 \
        run0 = fmaf(a3.z, R3.z, run0); const float i32 = run0;                 \
        run0 = fmaf(a3.w, R3.w, run0); const float i33 = run0;                 \
        float run1 = 0.0f;                                                     \
        run1 = fmaf(a4.x, R4.x, run1); const float i40 = run1;                 \
        run1 = fmaf(a4.y, R4.y, run1); const float i41 = run1;                 \
        run1 = fmaf(a4.z, R4.z, run1); const float i42 = run1;                 \
        run1 = fmaf(a4.w, R4.w, run1); const float i43 = run1;                 \
        run1 = fmaf(a5.x, R5.x, run1); const float i50 = run1;                 \
        run1 = fmaf(a5.y, R5.y, run1); const float i51 = run1;                 \
        run1 = fmaf(a5.z, R5.z, run1); const float i52 = run1;                 \
        run1 = fmaf(a5.w, R5.w, run1); const float i53 = run1;                 \
        run1 = fmaf(a6.x, R6.x, run1); const float i60 = run1;                 \
        run1 = fmaf(a6.y, R6.y, run1); const float i61 = run1;                 \
        run1 = fmaf(a6.z, R6.z, run1); const float i62 = run1;                 \
        run1 = fmaf(a6.w, R6.w, run1); const float i63 = run1;                 \
        run1 = fmaf(a7.x, R7.x, run1); const float i70 = run1;                 \
        run1 = fmaf(a7.y, R7.y, run1); const float i71 = run1;                 \
        run1 = fmaf(a7.z, R7.z, run1); const float i72 = run1;                 \
        run1 = fmaf(a7.w, R7.w, run1); const float i73 = run1;                 \
        const float tin = run0 + run1;                                         \
        const float tot = wave_incl_scan(tin);                                 \
        const float base = tot - tin;          /* exclusive over lanes */      \
        const float bhi = base + run0;                                         \
        a0.x = M0.x * (base + i00); a0.y = M0.y * (base + i01);                \
        a0.z = M0.z * (base + i02); a0.w = M0.w * (base + i03);                \
        a1.x = M1.x * (base + i10); a1.y = M1.y * (base + i11);                \
        a1.z = M1.z * (base + i12); a1.w = M1.w * (base + i13);                \
        a2.x = M2.x * (base + i20); a2.y = M2.y * (base + i21);                \
        a2.z = M2.z * (base + i22); a2.w = M2.w * (base + i23);                \
        a3.x = M3.x * (base + i30); a3.y = M3.y * (base + i31);                \
        a3.z = M3.z * (base + i32); a3.w = M3.w * (base + i33);                \
        a4.x = M4.x * (bhi + i40);  a4.y = M4.y * (bhi + i41);                 \
        a4.z = M4.z * (bhi + i42);  a4.w = M4.w * (bhi + i43);                 \
        a5.x = M5.x * (bhi + i50);  a5.y = M5.y * (bhi + i51);                 \
        a5.z = M5.z * (bhi + i52);  a5.w = M5.w * (bhi + i53);                 \
        a6.x = M6.x * (bhi + i60);  a6.y = M6.y * (bhi + i61);                 \
        a6.z = M6.z * (bhi + i62);  a6.w = M6.w * (bhi + i63);                 \
        a7.x = M7.x * (bhi + i70);  a7.y = M7.y * (bhi + i71);                 \
        a7.z = M7.z * (bhi + i72);  a7.w = M7.w * (bhi + i73);                 \
        float* o_ = arow + (size_t)i_ * KLEN;                                  \
        *(float4*)(o_ + 0)  = a0; *(float4*)(o_ + 4)  = a1;                    \
        *(float4*)(o_ + 8)  = a2; *(float4*)(o_ + 12) = a3;                    \
        *(float4*)(o_ + 16) = a4; *(float4*)(o_ + 20) = a5;                    \
        *(float4*)(o_ + 24) = a6; *(float4*)(o_ + 28) = a7;                    \
        /* unconditional clamped refill: consumed at step i+3 */               \
        const int rn_ = (i_ + 3 < QLEN) ? (i_ + 3) : (QLEN - 1);               \
        const float* mp_ = mrow + (size_t)rn_ * KLEN;                          \
        const float* rq_ = rrow + (size_t)rn_ * KLEN;                          \
        LOADROW8(M0,M1,M2,M3,M4,M5,M6,M7, mp_)                                 \
        LOADROW8(R0,R1,R2,R3,R4,R5,R6,R7, rq_)                                 \
    }

    // 255 = 85*3 steps in the 3-phase loop, then step 255 (phase A)
    for (int io = 0; io < 255; io += 3) {
        ASTEP(io + 0, mA0,mA1,mA2,mA3,mA4,mA5,mA6,mA7, rA0,rA1,rA2,rA3,rA4,rA5,rA6,rA7)
        ASTEP(io + 1, mB0,mB1,mB2,mB3,mB4,mB5,mB6,mB7, rB0,rB1,rB2,rB3,rB4,rB5,rB6,rB7)
        ASTEP(io + 2, mC0,mC1,mC2,mC3,mC4,mC5,mC6,mC7, rC0,rC1,rC2,rC3,rC4,rC5,rC6,rC7)
    }
    ASTEP(255, mA0,mA1,mA2,mA3,mA4,mA5,mA6,mA7, rA0,rA1,rA2,rA3,rA4,rA5,rA6,rA7)
#undef ASTEP
#undef LOADROW8
}

// ---------------------------------------------------------------------------
// beta: per (b,h,q) row of 2048 (e_chunk in d_out, overwritten)
// ---------------------------------------------------------------------------
__global__ __launch_bounds__(256) void beta_kernel(
    float* __restrict__ eo, const float* __restrict__ alpha)
{
    __shared__ float sse[KLEN + 3];
    __shared__ float su[KLEN + 3];
    __shared__ float wmax[4];

    const int tid = threadIdx.x;
    const int lane = tid & 63, wid = tid >> 6;
    const int row = blockIdx.x;                 // [B*H*Q]
    const int q = row & (QLEN - 1);
    const int b = row >> 10;
    float* erow = eo + (size_t)row * KLEN;
    const float* arow = alpha + ((size_t)b * QLEN + q) * KLEN;

    if (tid < 3) { sse[tid] = 0.0f; su[KLEN + tid] = 0.0f; }

    float ev[8];
    float lm = -INFINITY;
    #pragma unroll
    for (int j = 0; j < 8; ++j) {
        const int k = tid + 256 * j;
        ev[j] = erow[k];
        lm = fmaxf(lm, ev[j]);
    }
    #pragma unroll
    for (int off = 32; off > 0; off >>= 1) lm = fmaxf(lm, __shfl_xor(lm, off));
    if (lane == 0) wmax[wid] = lm;
    __syncthreads();
    const float mx = fmaxf(fmaxf(wmax[0], wmax[1]), fmaxf(wmax[2], wmax[3]));

    #pragma unroll
    for (int j = 0; j < 8; ++j) {
        const int k = tid + 256 * j;
        sse[k + 3] = fmaxf(__expf(ev[j] - mx), 1e-5f);
    }
    __syncthreads();

    #pragma unroll
    for (int j = 0; j < 8; ++j) {
        const int k = tid + 256 * j;
        const float denom = sse[k + 3] + sse[k + 2] + sse[k + 1] + sse[k];
        su[k] = arow[k] * __builtin_amdgcn_rcpf(denom);
    }
    __syncthreads();

    #pragma unroll
    for (int j = 0; j < 8; ++j) {
        const int k = tid + 256 * j;
        erow[k] = sse[k + 3] * (su[k] + su[k + 1] + su[k + 2] + su[k + 3]);
    }
}

// ---------------------------------------------------------------------------
extern "C" void kernel_launch(void* const* d_in, const int* in_sizes, int n_in,
                              void* d_out, int out_size, void* d_ws, size_t ws_size,
                              hipStream_t stream)
{
    (void)in_sizes; (void)n_in; (void)out_size; (void)ws_size;
    const float* key_enc = (const float*)d_in[0];   // [8,2048,512]
    const float* query   = (const float*)d_in[1];   // [8,256,512]
    const float* noise   = (const float*)d_in[2];   // [8,256,2048]
    const float* Wk_m    = (const float*)d_in[3];
    const float* bk_m    = (const float*)d_in[4];
    const float* Wq_m    = (const float*)d_in[5];
    const float* bq_m    = (const float*)d_in[6];
    const float* rp      = (const float*)d_in[7];
    const float* Wk_c    = (const float*)d_in[8];
    const float* bk_c    = (const float*)d_in[9];
    const float* Wq_c    = (const float*)d_in[10];
    const float* bq_c    = (const float*)d_in[11];
    float* out = (float*)d_out;                     // [8,4,256,2048]

    // workspace layout (bytes)
    char* w = (char*)d_ws;
    unsigned short* kx    = (unsigned short*)w; w += (size_t)BATCH * KLEN * KDIM * 2;   // 16.8 MB
    unsigned short* qx    = (unsigned short*)w; w += (size_t)BATCH * QLEN * KDIM * 2;   //  2.1 MB
    unsigned short* WTk   = (unsigned short*)w; w += (size_t)1024 * KDIM * 2;           //  1.0 MB
    unsigned short* WTq   = (unsigned short*)w; w += (size_t)1024 * KDIM * 2;           //  1.0 MB
    unsigned short* kproj = (unsigned short*)w; w += (size_t)BATCH * KLEN * 1024 * 2;   // 33.6 MB
    unsigned short* qproj = (unsigned short*)w; w += (size_t)BATCH * QLEN * 1024 * 2;   //  4.2 MB
    float* p_alpha = (float*)w; w += (size_t)BATCH * QLEN * KLEN * 4;                   // 16.8 MB
    float* mArr    = (float*)w; w += (size_t)BATCH * QLEN * KLEN * 4;                   // 16.8 MB
    float* rArr    = (float*)w;                                                         // 16.8 MB

    // 1) casts
    hipLaunchKernelGGL(cast_bf16, dim3(BATCH * KLEN * KDIM / 4 / 256), dim3(256), 0, stream,
                       key_enc, kx, BATCH * KLEN * KDIM / 4);
    hipLaunchKernelGGL(cast_bf16, dim3(BATCH * QLEN * KDIM / 4 / 256), dim3(256), 0, stream,
                       query, qx, BATCH * QLEN * KDIM / 4);
    hipLaunchKernelGGL(transpose_cast, dim3(16, 16), dim3(32, 8), 0, stream, Wk_m, WTk);
    hipLaunchKernelGGL(transpose_cast, dim3(16, 16), dim3(32, 8), 0, stream, Wk_c, WTk + (size_t)512 * KDIM);
    hipLaunchKernelGGL(transpose_cast, dim3(16, 16), dim3(32, 8), 0, stream, Wq_m, WTq);
    hipLaunchKernelGGL(transpose_cast, dim3(16, 16), dim3(32, 8), 0, stream, Wq_c, WTq + (size_t)512 * KDIM);

    // 2) projections (staged bf16 MFMA, fused bias, bf16 out)
    hipLaunchKernelGGL(proj_mfma, dim3(8, BATCH * KLEN / 128), dim3(256), 0, stream,
                       kx, WTk, bk_m, bk_c, kproj);
    hipLaunchKernelGGL(proj_mfma, dim3(8, BATCH * QLEN / 128), dim3(256), 0, stream,
                       qx, WTq, bq_m, bq_c, qproj);

    // 3) p_choose (staged bf16 MFMA + fast sigmoid epilogue)
    hipLaunchKernelGGL(pchoose_mfma, dim3(KLEN / 128, QLEN / 128, BATCH), dim3(256), 0, stream,
                       qproj, kproj, noise, rp, p_alpha);

    // 4) cumprod -> (m, r)  (parallel, absorbs all transcendentals)
    hipLaunchKernelGGL(cumprod_mr, dim3(BATCH * QLEN), dim3(256), 0, stream,
                       p_alpha, mArr, rArr);

    // 5) alpha recurrence (serial, single wave per batch, no barriers)
    hipLaunchKernelGGL(alpha_scan, dim3(BATCH), dim3(64), 0, stream,
                       mArr, rArr, p_alpha);

    // 6) e_chunk (staged bf16 MFMA) into d_out
    hipLaunchKernelGGL(echunk_mfma, dim3(KLEN / 128, QLEN / 128, BATCH * NHEADS), dim3(256), 0, stream,
                       qproj, kproj, out);

    // 7) beta (overwrites e_chunk rows in d_out)
    hipLaunchKernelGGL(beta_kernel, dim3(BATCH * NHEADS * QLEN), dim3(256), 0, stream,
                       out, p_alpha);
}

// Round 11
// 311.471 us; speedup vs baseline: 1.8123x; 1.8123x over previous
//
#include <hip/hip_runtime.h>
#include <math.h>

// Problem constants
#define BATCH   8
#define QLEN    256
#define KLEN    2048
#define KDIM    512
#define ADIMC   512
#define NHEADS  4
#define DKH     128
#define CHUNKW  4

static constexpr float INV_SCALE = 0.04419417382415922f; // 1/sqrt(512)
static constexpr float EPSV = 1e-6f;

typedef __attribute__((ext_vector_type(8))) short bf16x8;
typedef __attribute__((ext_vector_type(4))) float f32x4;

__device__ __forceinline__ unsigned short f2bf(float f) {
    unsigned u = __builtin_bit_cast(unsigned, f);
    u += 0x7fffu + ((u >> 16) & 1u);   // round-to-nearest-even
    return (unsigned short)(u >> 16);
}

// Barrier waiting only on LDS ops (lgkmcnt); global loads/stores stay in flight.
__device__ __forceinline__ void lds_barrier() {
    __asm__ volatile("s_waitcnt lgkmcnt(0)\n\ts_barrier" ::: "memory");
}

// Async global->LDS, 16 B per lane (wave-uniform base + lane*16 rule).
__device__ __forceinline__ void gload_lds16(const void* g, void* l) {
    __builtin_amdgcn_global_load_lds(
        (const __attribute__((address_space(1))) void*)g,
        (__attribute__((address_space(3))) void*)l, 16, 0, 0);
}

// ---------------------------------------------------------------------------
// Elementwise f32 -> bf16 cast (4 elems/thread)
// ---------------------------------------------------------------------------
__global__ __launch_bounds__(256) void cast_bf16(
    const float* __restrict__ x, unsigned short* __restrict__ y, int n4)
{
    int i = blockIdx.x * 256 + threadIdx.x;
    if (i < n4) {
        float4 v = ((const float4*)x)[i];
        ushort4 o;
        o.x = f2bf(v.x); o.y = f2bf(v.y); o.z = f2bf(v.z); o.w = f2bf(v.w);
        ((ushort4*)y)[i] = o;
    }
}

// ---------------------------------------------------------------------------
// Transpose-cast: W [512 x 512] (k-major rows) -> WT [512 x 512] bf16, WT[n][k]
// ---------------------------------------------------------------------------
__global__ __launch_bounds__(256) void transpose_cast(
    const float* __restrict__ W, unsigned short* __restrict__ WT)
{
    __shared__ float tile[32][33];
    const int tx = threadIdx.x;          // 0..31
    const int ty = threadIdx.y;          // 0..7
    const int k0 = blockIdx.y * 32, n0 = blockIdx.x * 32;
    #pragma unroll
    for (int i = 0; i < 32; i += 8)
        tile[ty + i][tx] = W[(size_t)(k0 + ty + i) * KDIM + n0 + tx];
    __syncthreads();
    #pragma unroll
    for (int i = 0; i < 32; i += 8)
        WT[(size_t)(n0 + ty + i) * KDIM + k0 + tx] = f2bf(tile[tx][ty + i]);
}

// ---------------------------------------------------------------------------
// Staged NT MFMA core: block computes 128x128 f32 tile of A[M,K] @ B[N,K]^T.
// 256 threads / 4 waves, each wave a 64x64 subtile.
// ---------------------------------------------------------------------------
template<int KSTEPS>
__device__ __forceinline__ void mfma_nt_staged(
    const unsigned short* __restrict__ A, const unsigned short* __restrict__ B,
    int lda, int ldb, int bm, int bn,
    unsigned short* AsLDS, unsigned short* BsLDS, f32x4 acc[4][4])
{
    const int t = threadIdx.x;
    const int wv = t >> 6, ln = t & 63;
    const int r = ln & 15, quad = ln >> 4;
    const int wm = (wv >> 1) * 64, wn = (wv & 1) * 64;
    const int srow = wv * 16 + (ln >> 2);
    const int scol = (ln & 3) * 8;

    for (int ks = 0; ks < KSTEPS; ++ks) {
        const int k0 = ks * 32;
        #pragma unroll
        for (int j = 0; j < 2; ++j) {
            gload_lds16(A + (size_t)(bm + j * 64 + srow) * lda + k0 + scol,
                        AsLDS + (size_t)(j * 64 + wv * 16) * 32);
            gload_lds16(B + (size_t)(bn + j * 64 + srow) * ldb + k0 + scol,
                        BsLDS + (size_t)(j * 64 + wv * 16) * 32);
        }
        __syncthreads();
        bf16x8 af[4], bg[4];
        #pragma unroll
        for (int f = 0; f < 4; ++f)
            af[f] = *(const bf16x8*)(AsLDS + (size_t)(wm + f * 16 + r) * 32 + quad * 8);
        #pragma unroll
        for (int f = 0; f < 4; ++f)
            bg[f] = *(const bf16x8*)(BsLDS + (size_t)(wn + f * 16 + r) * 32 + quad * 8);
        #pragma unroll
        for (int i = 0; i < 4; ++i)
            #pragma unroll
            for (int j2 = 0; j2 < 4; ++j2)
                acc[i][j2] = __builtin_amdgcn_mfma_f32_16x16x32_bf16(
                    af[i], bg[j2], acc[i][j2], 0, 0, 0);
        __syncthreads();
    }
}

__device__ __forceinline__ void zero_acc(f32x4 acc[4][4]) {
    #pragma unroll
    for (int i = 0; i < 4; ++i)
        #pragma unroll
        for (int j = 0; j < 4; ++j)
            acc[i][j] = f32x4{0.f, 0.f, 0.f, 0.f};
}

// ---------------------------------------------------------------------------
// Projection: C[M x 1024] bf16 = A[M x 512] @ WT[1024 x 512]^T + bias
// ---------------------------------------------------------------------------
__global__ __launch_bounds__(256) void proj_mfma(
    const unsigned short* __restrict__ A, const unsigned short* __restrict__ WT,
    const float* __restrict__ bias_m, const float* __restrict__ bias_c,
    unsigned short* __restrict__ C)
{
    __shared__ unsigned short As[128 * 32];
    __shared__ unsigned short Bs[128 * 32];
    const int bm = blockIdx.y * 128, bn = blockIdx.x * 128;
    f32x4 acc[4][4]; zero_acc(acc);
    mfma_nt_staged<16>(A, WT, KDIM, KDIM, bm, bn, As, Bs, acc);
    const int wv = threadIdx.x >> 6, ln = threadIdx.x & 63;
    const int r = ln & 15, quad = ln >> 4;
    const int m0 = bm + (wv >> 1) * 64, n0 = bn + (wv & 1) * 64;
    #pragma unroll
    for (int j = 0; j < 4; ++j) {
        const int n = n0 + j * 16 + r;
        const float bv = (n < 512) ? bias_m[n] : bias_c[n - 512];
        #pragma unroll
        for (int i = 0; i < 4; ++i) {
            #pragma unroll
            for (int reg = 0; reg < 4; ++reg) {
                const int m = m0 + i * 16 + quad * 4 + reg;
                C[(size_t)m * 1024 + n] = f2bf(acc[i][j][reg] + bv);
            }
        }
    }
}

// ---------------------------------------------------------------------------
// p_choose: per batch b, p = sigmoid(qm[b] @ km[b]^T / sqrt(512) + r + noise)
// ---------------------------------------------------------------------------
__global__ __launch_bounds__(256) void pchoose_mfma(
    const unsigned short* __restrict__ qp, const unsigned short* __restrict__ kp,
    const float* __restrict__ noise, const float* __restrict__ rp,
    float* __restrict__ p)
{
    __shared__ unsigned short As[128 * 32];
    __shared__ unsigned short Bs[128 * 32];
    const int b = blockIdx.z;
    const unsigned short* A = qp + (size_t)b * QLEN * 1024;
    const unsigned short* B = kp + (size_t)b * KLEN * 1024;
    const int bm = blockIdx.y * 128, bn = blockIdx.x * 128;
    f32x4 acc[4][4]; zero_acc(acc);
    mfma_nt_staged<16>(A, B, 1024, 1024, bm, bn, As, Bs, acc);
    const int wv = threadIdx.x >> 6, ln = threadIdx.x & 63;
    const int r = ln & 15, quad = ln >> 4;
    const int m0 = bm + (wv >> 1) * 64, n0 = bn + (wv & 1) * 64;
    const float rv = rp[0];
    #pragma unroll
    for (int i = 0; i < 4; ++i) {
        #pragma unroll
        for (int reg = 0; reg < 4; ++reg) {
            const int q = m0 + i * 16 + quad * 4 + reg;
            const size_t rowoff = ((size_t)b * QLEN + q) * KLEN;
            #pragma unroll
            for (int j = 0; j < 4; ++j) {
                const int k = n0 + j * 16 + r;
                const float e = acc[i][j][reg] * INV_SCALE + rv + noise[rowoff + k];
                p[rowoff + k] = __builtin_amdgcn_rcpf(1.0f + __expf(-e));
            }
        }
    }
}

// ---------------------------------------------------------------------------
// 64-lane inclusive prefix sum via DPP (≈6 VALU ops)
// ---------------------------------------------------------------------------
__device__ __forceinline__ float wave_incl_scan(float x)
{
#define DPP_ADD(ctrl, rmask, bctrl)                                            \
    { int _t = __builtin_amdgcn_update_dpp(0, __builtin_bit_cast(int, x),      \
                                           ctrl, rmask, 0xf, bctrl);           \
      x += __builtin_bit_cast(float, _t); }
    DPP_ADD(0x111, 0xf, true)   // row_shr:1
    DPP_ADD(0x112, 0xf, true)   // row_shr:2
    DPP_ADD(0x114, 0xf, true)   // row_shr:4
    DPP_ADD(0x118, 0xf, true)   // row_shr:8
    DPP_ADD(0x142, 0xa, false)  // row_bcast:15 -> rows 1,3
    DPP_ADD(0x143, 0xc, false)  // row_bcast:31 -> rows 2,3
#undef DPP_ADD
    return x;
}

// ---------------------------------------------------------------------------
// cumprod_mr: per (b,q) row: cp = exp(excl_cumsum(log(clip(1-p)))); emits
// m = p*cp, r = 1/clip(cp). Fast intrinsics; absorbs all transcendentals.
// ---------------------------------------------------------------------------
__global__ __launch_bounds__(256) void cumprod_mr(
    const float* __restrict__ p, float* __restrict__ mArr, float* __restrict__ rArr)
{
    const size_t row = blockIdx.x;
    const float* pr = p + row * KLEN;
    float* mr = mArr + row * KLEN;
    float* rr = rArr + row * KLEN;
    const int tid = threadIdx.x;
    const int lane = tid & 63, wid = tid >> 6;
    __shared__ float waveTot[4];

    float4 v0 = *(const float4*)(pr + tid * 8);
    float4 v1 = *(const float4*)(pr + tid * 8 + 4);
    float pv[8] = {v0.x, v0.y, v0.z, v0.w, v1.x, v1.y, v1.z, v1.w};
    float excl[8];
    float run = 0.0f;
    #pragma unroll
    for (int j = 0; j < 8; ++j) {
        float l = __logf(fminf(fmaxf(1.0f - pv[j], EPSV), 1.0f));
        excl[j] = run;
        run += l;
    }
    float s = wave_incl_scan(run);
    if (lane == 63) waveTot[wid] = s;
    __syncthreads();
    float wex = 0.0f;
    for (int w = 0; w < wid; ++w) wex += waveTot[w];
    const float texcl = wex + s - run;

    float mv[8], rv[8];
    #pragma unroll
    for (int j = 0; j < 8; ++j) {
        const float cpv = __expf(texcl + excl[j]);
        mv[j] = pv[j] * cpv;
        rv[j] = __builtin_amdgcn_rcpf(fminf(fmaxf(cpv, EPSV), 1.0f));
    }
    *(float4*)(mr + tid * 8)     = *(float4*)&mv[0];
    *(float4*)(mr + tid * 8 + 4) = *(float4*)&mv[4];
    *(float4*)(rr + tid * 8)     = *(float4*)&rv[0];
    *(float4*)(rr + tid * 8 + 4) = *(float4*)&rv[4];
}

// ---------------------------------------------------------------------------
// alpha_echunk: FUSED kernel. Blocks 0..7: the R9 8-wave alpha recurrence
// (78.6 us, proven; coalesced 4-elems/lane layout). Blocks 8..1031: e_chunk
// MFMA tiles (independent of alpha — only needs projections). Fusing lets
// the 1024 echunk blocks fill the 248 CUs that sit idle during the serial
// alpha scan (same-stream dispatches otherwise serialize; events/streams are
// banned under graph capture). Echunk blocks use waves 0..3 for work; all 8
// waves execute the identical __syncthreads() sequence (no early exit UB).
// ---------------------------------------------------------------------------
__global__ __launch_bounds__(512, 1) void alpha_echunk(
    const float* __restrict__ mArr, const float* __restrict__ rArr,
    float* __restrict__ alpha,
    const unsigned short* __restrict__ qp, const unsigned short* __restrict__ kp,
    float* __restrict__ out)
{
    __shared__ __align__(16) char smem[16384];
    const int bid = blockIdx.x;
    const int tid = threadIdx.x;

    if (bid < BATCH) {
        // ---------------- alpha scan (R9 structure) ----------------
        float (*wt)[8] = (float (*)[8])smem;   // [2][8]
        const int lane = tid & 63, wid = tid >> 6;
        const float* mrow = mArr + (size_t)bid * QLEN * KLEN + tid * 4;
        const float* rrow = rArr + (size_t)bid * QLEN * KLEN + tid * 4;
        float* arow = alpha + (size_t)bid * QLEN * KLEN + tid * 4;

        float aw0 = 0.f, aw1 = 0.f, aw2 = 0.f, aw3 = 0.f;
        if (tid == 0) aw0 = 1.0f;   // aw_prev one-hot at k=0

        float4 mA = *(const float4*)(mrow);
        float4 rA = *(const float4*)(rrow);
        float4 mB = *(const float4*)(mrow + KLEN);
        float4 rB = *(const float4*)(rrow + KLEN);

#define ASTEP(I, MREG, RREG)                                                   \
    {                                                                          \
        const int i_ = (I);                                                    \
        float4 mc = MREG, rc = RREG;                                           \
        const int rn_ = (i_ + 2 < QLEN) ? (i_ + 2) : (QLEN - 1);               \
        MREG = *(const float4*)(mrow + (size_t)rn_ * KLEN);                    \
        RREG = *(const float4*)(rrow + (size_t)rn_ * KLEN);                    \
        float run = 0.0f, i0, i1, i2, i3;                                      \
        run = fmaf(aw0, rc.x, run); i0 = run;                                  \
        run = fmaf(aw1, rc.y, run); i1 = run;                                  \
        run = fmaf(aw2, rc.z, run); i2 = run;                                  \
        run = fmaf(aw3, rc.w, run); i3 = run;                                  \
        float tot = wave_incl_scan(run);                                       \
        if (lane == 63) wt[i_ & 1][wid] = tot;                                 \
        lds_barrier();                                                         \
        float base = tot - run;                                                \
        float4 w0 = *(const float4*)&wt[i_ & 1][0];                            \
        float4 w1 = *(const float4*)&wt[i_ & 1][4];                            \
        if (wid > 0) base += w0.x;                                             \
        if (wid > 1) base += w0.y;                                             \
        if (wid > 2) base += w0.z;                                             \
        if (wid > 3) base += w0.w;                                             \
        if (wid > 4) base += w1.x;                                             \
        if (wid > 5) base += w1.y;                                             \
        if (wid > 6) base += w1.z;                                             \
        aw0 = mc.x * (base + i0);                                              \
        aw1 = mc.y * (base + i1);                                              \
        aw2 = mc.z * (base + i2);                                              \
        aw3 = mc.w * (base + i3);                                              \
        float4 ov; ov.x = aw0; ov.y = aw1; ov.z = aw2; ov.w = aw3;             \
        *(float4*)(arow + (size_t)i_ * KLEN) = ov;                             \
    }

        for (int io = 0; io < QLEN; io += 2) {
            ASTEP(io + 0, mA, rA)
            ASTEP(io + 1, mB, rB)
        }
#undef ASTEP
        return;
    }

    // ---------------- echunk tile ----------------
    const int v = bid - BATCH;           // 0..1023
    const int z = v >> 5;                // 0..31 = b*4+h
    const int by = (v >> 4) & 1;
    const int bx = v & 15;
    const int b = z >> 2, h = z & 3;
    const bool worker = tid < 256;
    unsigned short* As = (unsigned short*)smem;            // 8 KB
    unsigned short* Bs = (unsigned short*)(smem + 8192);   // 8 KB
    const unsigned short* A = qp + (size_t)b * QLEN * 1024 + 512 + h * DKH;
    const unsigned short* B = kp + (size_t)b * KLEN * 1024 + 512 + h * DKH;
    const int bm = by * 128, bn = bx * 128;

    const int wv = tid >> 6, ln = tid & 63;
    const int r = ln & 15, quad = ln >> 4;
    const int wm = (wv >> 1) * 64, wn = (wv & 1) * 64;
    const int srow = (wv & 3) * 16 + (ln >> 2);
    const int scol = (ln & 3) * 8;

    f32x4 acc[4][4]; zero_acc(acc);
    for (int ks = 0; ks < 4; ++ks) {
        const int k0 = ks * 32;
        if (worker) {
            #pragma unroll
            for (int j = 0; j < 2; ++j) {
                gload_lds16(A + (size_t)(bm + j * 64 + srow) * 1024 + k0 + scol,
                            As + (size_t)(j * 64 + wv * 16) * 32);
                gload_lds16(B + (size_t)(bn + j * 64 + srow) * 1024 + k0 + scol,
                            Bs + (size_t)(j * 64 + wv * 16) * 32);
            }
        }
        __syncthreads();
        if (worker) {
            bf16x8 af[4], bg[4];
            #pragma unroll
            for (int f = 0; f < 4; ++f)
                af[f] = *(const bf16x8*)(As + (size_t)(wm + f * 16 + r) * 32 + quad * 8);
            #pragma unroll
            for (int f = 0; f < 4; ++f)
                bg[f] = *(const bf16x8*)(Bs + (size_t)(wn + f * 16 + r) * 32 + quad * 8);
            #pragma unroll
            for (int i = 0; i < 4; ++i)
                #pragma unroll
                for (int j2 = 0; j2 < 4; ++j2)
                    acc[i][j2] = __builtin_amdgcn_mfma_f32_16x16x32_bf16(
                        af[i], bg[j2], acc[i][j2], 0, 0, 0);
        }
        __syncthreads();
    }
    if (worker) {
        const int m0 = bm + (wv >> 1) * 64, n0 = bn + (wv & 1) * 64;
        #pragma unroll
        for (int i = 0; i < 4; ++i) {
            #pragma unroll
            for (int reg = 0; reg < 4; ++reg) {
                const int q = m0 + i * 16 + quad * 4 + reg;
                const size_t rowoff = ((size_t)z * QLEN + q) * KLEN;
                #pragma unroll
                for (int j = 0; j < 4; ++j) {
                    const int k = n0 + j * 16 + r;
                    out[rowoff + k] = acc[i][j][reg] * INV_SCALE;
                }
            }
        }
    }
}

// ---------------------------------------------------------------------------
// beta: per (b,h,q) row of 2048 (e_chunk in d_out, overwritten)
// ---------------------------------------------------------------------------
__global__ __launch_bounds__(256) void beta_kernel(
    float* __restrict__ eo, const float* __restrict__ alpha)
{
    __shared__ float sse[KLEN + 3];
    __shared__ float su[KLEN + 3];
    __shared__ float wmax[4];

    const int tid = threadIdx.x;
    const int lane = tid & 63, wid = tid >> 6;
    const int row = blockIdx.x;                 // [B*H*Q]
    const int q = row & (QLEN - 1);
    const int b = row >> 10;
    float* erow = eo + (size_t)row * KLEN;
    const float* arow = alpha + ((size_t)b * QLEN + q) * KLEN;

    if (tid < 3) { sse[tid] = 0.0f; su[KLEN + tid] = 0.0f; }

    float ev[8];
    float lm = -INFINITY;
    #pragma unroll
    for (int j = 0; j < 8; ++j) {
        const int k = tid + 256 * j;
        ev[j] = erow[k];
        lm = fmaxf(lm, ev[j]);
    }
    #pragma unroll
    for (int off = 32; off > 0; off >>= 1) lm = fmaxf(lm, __shfl_xor(lm, off));
    if (lane == 0) wmax[wid] = lm;
    __syncthreads();
    const float mx = fmaxf(fmaxf(wmax[0], wmax[1]), fmaxf(wmax[2], wmax[3]));

    #pragma unroll
    for (int j = 0; j < 8; ++j) {
        const int k = tid + 256 * j;
        sse[k + 3] = fmaxf(__expf(ev[j] - mx), 1e-5f);
    }
    __syncthreads();

    #pragma unroll
    for (int j = 0; j < 8; ++j) {
        const int k = tid + 256 * j;
        const float denom = sse[k + 3] + sse[k + 2] + sse[k + 1] + sse[k];
        su[k] = arow[k] * __builtin_amdgcn_rcpf(denom);
    }
    __syncthreads();

    #pragma unroll
    for (int j = 0; j < 8; ++j) {
        const int k = tid + 256 * j;
        erow[k] = sse[k + 3] * (su[k] + su[k + 1] + su[k + 2] + su[k + 3]);
    }
}

// ---------------------------------------------------------------------------
extern "C" void kernel_launch(void* const* d_in, const int* in_sizes, int n_in,
                              void* d_out, int out_size, void* d_ws, size_t ws_size,
                              hipStream_t stream)
{
    (void)in_sizes; (void)n_in; (void)out_size; (void)ws_size;
    const float* key_enc = (const float*)d_in[0];   // [8,2048,512]
    const float* query   = (const float*)d_in[1];   // [8,256,512]
    const float* noise   = (const float*)d_in[2];   // [8,256,2048]
    const float* Wk_m    = (const float*)d_in[3];
    const float* bk_m    = (const float*)d_in[4];
    const float* Wq_m    = (const float*)d_in[5];
    const float* bq_m    = (const float*)d_in[6];
    const float* rp      = (const float*)d_in[7];
    const float* Wk_c    = (const float*)d_in[8];
    const float* bk_c    = (const float*)d_in[9];
    const float* Wq_c    = (const float*)d_in[10];
    const float* bq_c    = (const float*)d_in[11];
    float* out = (float*)d_out;                     // [8,4,256,2048]

    // workspace layout (bytes)
    char* w = (char*)d_ws;
    unsigned short* kx    = (unsigned short*)w; w += (size_t)BATCH * KLEN * KDIM * 2;   // 16.8 MB
    unsigned short* qx    = (unsigned short*)w; w += (size_t)BATCH * QLEN * KDIM * 2;   //  2.1 MB
    unsigned short* WTk   = (unsigned short*)w; w += (size_t)1024 * KDIM * 2;           //  1.0 MB
    unsigned short* WTq   = (unsigned short*)w; w += (size_t)1024 * KDIM * 2;           //  1.0 MB
    unsigned short* kproj = (unsigned short*)w; w += (size_t)BATCH * KLEN * 1024 * 2;   // 33.6 MB
    unsigned short* qproj = (unsigned short*)w; w += (size_t)BATCH * QLEN * 1024 * 2;   //  4.2 MB
    float* p_alpha = (float*)w; w += (size_t)BATCH * QLEN * KLEN * 4;                   // 16.8 MB
    float* mArr    = (float*)w; w += (size_t)BATCH * QLEN * KLEN * 4;                   // 16.8 MB
    float* rArr    = (float*)w;                                                         // 16.8 MB

    // 1) casts
    hipLaunchKernelGGL(cast_bf16, dim3(BATCH * KLEN * KDIM / 4 / 256), dim3(256), 0, stream,
                       key_enc, kx, BATCH * KLEN * KDIM / 4);
    hipLaunchKernelGGL(cast_bf16, dim3(BATCH * QLEN * KDIM / 4 / 256), dim3(256), 0, stream,
                       query, qx, BATCH * QLEN * KDIM / 4);
    hipLaunchKernelGGL(transpose_cast, dim3(16, 16), dim3(32, 8), 0, stream, Wk_m, WTk);
    hipLaunchKernelGGL(transpose_cast, dim3(16, 16), dim3(32, 8), 0, stream, Wk_c, WTk + (size_t)512 * KDIM);
    hipLaunchKernelGGL(transpose_cast, dim3(16, 16), dim3(32, 8), 0, stream, Wq_m, WTq);
    hipLaunchKernelGGL(transpose_cast, dim3(16, 16), dim3(32, 8), 0, stream, Wq_c, WTq + (size_t)512 * KDIM);

    // 2) projections (staged bf16 MFMA, fused bias, bf16 out)
    hipLaunchKernelGGL(proj_mfma, dim3(8, BATCH * KLEN / 128), dim3(256), 0, stream,
                       kx, WTk, bk_m, bk_c, kproj);
    hipLaunchKernelGGL(proj_mfma, dim3(8, BATCH * QLEN / 128), dim3(256), 0, stream,
                       qx, WTq, bq_m, bq_c, qproj);

    // 3) p_choose (staged bf16 MFMA + fast sigmoid epilogue)
    hipLaunchKernelGGL(pchoose_mfma, dim3(KLEN / 128, QLEN / 128, BATCH), dim3(256), 0, stream,
                       qproj, kproj, noise, rp, p_alpha);

    // 4) cumprod -> (m, r)  (parallel, absorbs all transcendentals)
    hipLaunchKernelGGL(cumprod_mr, dim3(BATCH * QLEN), dim3(256), 0, stream,
                       p_alpha, mArr, rArr);

    // 5) FUSED: alpha recurrence (blocks 0..7) + e_chunk (blocks 8..1031)
    hipLaunchKernelGGL(alpha_echunk, dim3(BATCH + KLEN / 128 * QLEN / 128 * BATCH * NHEADS),
                       dim3(512), 0, stream,
                       mArr, rArr, p_alpha, qproj, kproj, out);

    // 6) beta (overwrites e_chunk rows in d_out)
    hipLaunchKernelGGL(beta_kernel, dim3(BATCH * NHEADS * QLEN), dim3(256), 0, stream,
                       out, p_alpha);
}